// Round 1
// 1108.991 us; speedup vs baseline: 2.4715x; 2.4715x over previous
//
#include <hip/hip_runtime.h>
#include <hip/hip_bf16.h>

// Problem constants
#define NROWS 32768
#define DDIM  512
#define KSZ_  4096
#define EMA_DECAY_ 0.99f
#define EPS_ 1e-5f

// MFMA GEMM-argmin tiling
#define BM 128            // rows of f per block
#define BN 128            // codebook cols per chunk
#define NCHUNK 4          // column chunks per block
#define CSPLIT 8          // N-dim split across blocks (grid.y)
#define BK 32             // fp32 k per K-step
#define LDA 40            // shorts per LDS tile row (32 data + 8 pad; 80B rows, 16B-aligned)

typedef float f32x4 __attribute__((ext_vector_type(4)));
typedef __bf16 bf16x8 __attribute__((ext_vector_type(8)));

// ---------------------------------------------------------------------------
// Kernel 1: Kt2[j] = sum_d K[j][d]^2   (one wave per row)
// ---------------------------------------------------------------------------
__global__ __launch_bounds__(256) void kt2_kernel(const float* __restrict__ K,
                                                  float* __restrict__ Kt2) {
    int gid  = blockIdx.x * 256 + threadIdx.x;
    int row  = gid >> 6;
    int lane = threadIdx.x & 63;
    const float* kr = K + (size_t)row * DDIM;
    float s = 0.f;
#pragma unroll
    for (int u = 0; u < 2; u++) {
        float4 v = *(const float4*)&kr[u * 256 + lane * 4];
        s += v.x * v.x + v.y * v.y + v.z * v.z + v.w * v.w;
    }
#pragma unroll
    for (int off = 1; off < 64; off <<= 1) s += __shfl_xor(s, off, 64);
    if (lane == 0) Kt2[row] = s;
}

// ---------------------------------------------------------------------------
// split fp32 -> bf16 hi + bf16 lo (hi = RNE(x), lo = RNE(x - hi))
// ---------------------------------------------------------------------------
__device__ __forceinline__ void cvt8(const float4 x0, const float4 x1,
                                     bf16x8& h, bf16x8& l) {
    float xs[8] = {x0.x, x0.y, x0.z, x0.w, x1.x, x1.y, x1.z, x1.w};
#pragma unroll
    for (int j = 0; j < 8; j++) {
        __bf16 hj = (__bf16)xs[j];
        h[j] = hj;
        l[j] = (__bf16)(xs[j] - (float)hj);
    }
}

// ---------------------------------------------------------------------------
// Kernel 2: fused bf16x3 MFMA GEMM + argmin.
// score = 0.5*|K[j]|^2 - f.K[j]  (same argmin ordering as squared distance)
// f.K computed as f_hi.K_hi + f_hi.K_lo + f_lo.K_hi  (error ~1e-4 absolute)
// Block: BM rows x (BN*NCHUNK) cols; grid.y = CSPLIT splits of the N dim.
// 4 waves in 2x2; wave computes 64x64 via 4x4 fragments of 16x16x32 MFMA.
// ---------------------------------------------------------------------------
__global__ __launch_bounds__(256, 2) void argmin_kernel(
    const float* __restrict__ f, const float* __restrict__ K,
    const float* __restrict__ Kt2,
    float* __restrict__ bestd, int* __restrict__ bestidx) {

    __shared__ __align__(16) __bf16 Ah[BM * LDA];
    __shared__ __align__(16) __bf16 Al[BM * LDA];
    __shared__ __align__(16) __bf16 Bh[BN * LDA];
    __shared__ __align__(16) __bf16 Bl[BN * LDA];
    __shared__ float redD[2][BM];
    __shared__ int   redI[2][BM];

    const int tid  = threadIdx.x;
    const int lane = tid & 63;
    const int w    = tid >> 6;
    const int wr   = w >> 1;       // wave row (0..1)
    const int wc   = w & 1;        // wave col (0..1)
    const int l15  = lane & 15;
    const int l4   = lane >> 4;
    const int row0 = blockIdx.x * BM;
    const int split = blockIdx.y;
    const int col0  = split * (BN * NCHUNK);

    float best[16];
    int   bidx[16];
#pragma unroll
    for (int i = 0; i < 16; i++) { best[i] = 3.4e38f; bidx[i] = 0x7fffffff; }

    for (int chunk = 0; chunk < NCHUNK; ++chunk) {
        const int c0 = col0 + chunk * BN;
        f32x4 acc[4][4];
#pragma unroll
        for (int m = 0; m < 4; m++)
#pragma unroll
            for (int n = 0; n < 4; n++)
                acc[m][n] = (f32x4){0.f, 0.f, 0.f, 0.f};

        for (int ks = 0; ks < DDIM; ks += BK) {
            __syncthreads();
            // stage A: 128 rows x 32 fp32 -> hi/lo bf16 tiles.
            // granule = 8 contiguous cols of one row; 512 granules, 2/thread.
#pragma unroll
            for (int v = 0; v < 2; v++) {
                int g  = v * 256 + tid;
                int r  = g >> 2;
                int c8 = (g & 3) * 8;
                const float* src = f + (size_t)(row0 + r) * DDIM + ks + c8;
                float4 x0 = *(const float4*)src;
                float4 x1 = *(const float4*)(src + 4);
                bf16x8 h, lo;
                cvt8(x0, x1, h, lo);
                *(bf16x8*)&Ah[r * LDA + c8] = h;
                *(bf16x8*)&Al[r * LDA + c8] = lo;
            }
            // stage B: 128 code rows x 32 fp32 -> hi/lo bf16 tiles
#pragma unroll
            for (int v = 0; v < 2; v++) {
                int g  = v * 256 + tid;
                int r  = g >> 2;
                int c8 = (g & 3) * 8;
                const float* src = K + (size_t)(c0 + r) * DDIM + ks + c8;
                float4 x0 = *(const float4*)src;
                float4 x1 = *(const float4*)(src + 4);
                bf16x8 h, lo;
                cvt8(x0, x1, h, lo);
                *(bf16x8*)&Bh[r * LDA + c8] = h;
                *(bf16x8*)&Bl[r * LDA + c8] = lo;
            }
            __syncthreads();

            // fragment loads: lane l reads row (frag_row + l&15), k-bytes (l>>4)*16
            bf16x8 ah[4], al[4], bh[4], bl[4];
#pragma unroll
            for (int m = 0; m < 4; m++) {
                int off = (wr * 64 + m * 16 + l15) * LDA + l4 * 8;
                ah[m] = *(const bf16x8*)&Ah[off];
                al[m] = *(const bf16x8*)&Al[off];
            }
#pragma unroll
            for (int n = 0; n < 4; n++) {
                int off = (wc * 64 + n * 16 + l15) * LDA + l4 * 8;
                bh[n] = *(const bf16x8*)&Bh[off];
                bl[n] = *(const bf16x8*)&Bl[off];
            }
            // 48 MFMAs: hi*hi + hi*lo + lo*hi
#pragma unroll
            for (int m = 0; m < 4; m++)
#pragma unroll
                for (int n = 0; n < 4; n++)
                    acc[m][n] = __builtin_amdgcn_mfma_f32_16x16x32_bf16(ah[m], bh[n], acc[m][n], 0, 0, 0);
#pragma unroll
            for (int m = 0; m < 4; m++)
#pragma unroll
                for (int n = 0; n < 4; n++)
                    acc[m][n] = __builtin_amdgcn_mfma_f32_16x16x32_bf16(ah[m], bl[n], acc[m][n], 0, 0, 0);
#pragma unroll
            for (int m = 0; m < 4; m++)
#pragma unroll
                for (int n = 0; n < 4; n++)
                    acc[m][n] = __builtin_amdgcn_mfma_f32_16x16x32_bf16(al[m], bh[n], acc[m][n], 0, 0, 0);
        }

        // chunk epilogue: argmin update. acc[m][n][q] is output
        // row = wr*64 + m*16 + l4*4 + q, col = wc*64 + n*16 + l15.
        float kt2c[4];
#pragma unroll
        for (int n = 0; n < 4; n++) kt2c[n] = Kt2[c0 + wc * 64 + n * 16 + l15];
#pragma unroll
        for (int m = 0; m < 4; m++)
#pragma unroll
            for (int q = 0; q < 4; q++) {
                float d = 3.4e38f; int bi = 0x7fffffff;
#pragma unroll
                for (int n = 0; n < 4; n++) {
                    float s = 0.5f * kt2c[n] - acc[m][n][q];
                    int col = c0 + wc * 64 + n * 16 + l15;
                    if (s < d || (s == d && col < bi)) { d = s; bi = col; }
                }
                int i16 = m * 4 + q;
                if (d < best[i16] || (d == best[i16] && bi < bidx[i16])) {
                    best[i16] = d; bidx[i16] = bi;
                }
            }
    }

    // cross-lane reduce within 16-lane groups (same rows), then cross-wave
#pragma unroll
    for (int i = 0; i < 16; i++) {
        float d = best[i]; int bi = bidx[i];
#pragma unroll
        for (int off = 1; off < 16; off <<= 1) {
            float od = __shfl_xor(d, off, 64);
            int   oi = __shfl_xor(bi, off, 64);
            if (od < d || (od == d && oi < bi)) { d = od; bi = oi; }
        }
        if (l15 == 0) {
            int m = i >> 2, q = i & 3;
            int rl = wr * 64 + m * 16 + l4 * 4 + q;
            redD[wc][rl] = d;
            redI[wc][rl] = bi;
        }
    }
    __syncthreads();
    if (tid < BM) {
        float d0 = redD[0][tid], d1 = redD[1][tid];
        int   i0 = redI[0][tid], i1 = redI[1][tid];
        if (d1 < d0 || (d1 == d0 && i1 < i0)) { d0 = d1; i0 = i1; }
        bestd[(size_t)(row0 + tid) * CSPLIT + split]   = d0;
        bestidx[(size_t)(row0 + tid) * CSPLIT + split] = i0;
    }
}

// ---------------------------------------------------------------------------
// Kernel 3: per-row split-reduce, gather K[k1] -> f_ipmlm, loss partial,
// scatter counts/dw via atomics. One wave per row.
// ---------------------------------------------------------------------------
__global__ __launch_bounds__(256) void gather_kernel(
    const float* __restrict__ f, const float* __restrict__ K,
    const float* __restrict__ bestd, const int* __restrict__ bestidx,
    float* __restrict__ out_fipm, float* __restrict__ loss_sum,
    float* __restrict__ counts, float* __restrict__ dw) {
    int gid  = blockIdx.x * 256 + threadIdx.x;
    int row  = gid >> 6;
    int lane = threadIdx.x & 63;

    float d = bestd[(size_t)row * CSPLIT];
    int  bi = bestidx[(size_t)row * CSPLIT];
#pragma unroll
    for (int s = 1; s < CSPLIT; s++) {
        float od = bestd[(size_t)row * CSPLIT + s];
        int   oi = bestidx[(size_t)row * CSPLIT + s];
        if (od < d || (od == d && oi < bi)) { d = od; bi = oi; }
    }

    const float* frow = f + (size_t)row * DDIM;
    const float* krow = K + (size_t)bi * DDIM;
    float lsum = 0.f;
#pragma unroll
    for (int u = 0; u < 2; u++) {
        int off = u * 256 + lane * 4;
        float4 fv = *(const float4*)&frow[off];
        float4 kv = *(const float4*)&krow[off];
        *(float4*)&out_fipm[(size_t)row * DDIM + off] = kv;
        float dx = kv.x - fv.x, dy = kv.y - fv.y, dz = kv.z - fv.z, dwv = kv.w - fv.w;
        lsum += dx * dx + dy * dy + dz * dz + dwv * dwv;
        float* dst = &dw[(size_t)bi * DDIM + off];
        atomicAdd(dst + 0, fv.x);
        atomicAdd(dst + 1, fv.y);
        atomicAdd(dst + 2, fv.z);
        atomicAdd(dst + 3, fv.w);
    }
#pragma unroll
    for (int off = 1; off < 64; off <<= 1) lsum += __shfl_xor(lsum, off, 64);
    if (lane == 0) {
        atomicAdd(loss_sum, lsum);
        atomicAdd(&counts[bi], 1.0f);
    }
}

// ---------------------------------------------------------------------------
// Kernel 4: new_ecs = 0.99*ecs + 0.01*counts; n = sum(new_ecs)
// ---------------------------------------------------------------------------
__global__ __launch_bounds__(256) void ecs_kernel(
    const float* __restrict__ ecs_in, const float* __restrict__ counts,
    float* __restrict__ out_ecs, float* __restrict__ n_sum) {
    int i = blockIdx.x * 256 + threadIdx.x;
    float v = ecs_in[i] * EMA_DECAY_ + (1.0f - EMA_DECAY_) * counts[i];
    out_ecs[i] = v;
    float s = v;
#pragma unroll
    for (int off = 1; off < 64; off <<= 1) s += __shfl_xor(s, off, 64);
    if ((threadIdx.x & 63) == 0) atomicAdd(n_sum, s);
}

// ---------------------------------------------------------------------------
// Kernel 5: new_ema_w = 0.99*ema_w + 0.01*dw; new_K = new_ema_w / smoothed
// out_K / out_emaw are at odd float offsets -> scalar stores only.
// ---------------------------------------------------------------------------
__global__ __launch_bounds__(256) void final_kernel(
    const float* __restrict__ ema_w, const float* __restrict__ dw,
    const float* __restrict__ out_ecs, const float* __restrict__ n_sum,
    const float* __restrict__ loss_sum,
    float* __restrict__ out_K, float* __restrict__ out_emaw,
    float* __restrict__ out_loss) {
    int idx4 = blockIdx.x * 256 + threadIdx.x;   // 0..524287 (float4 granules)
    int row  = idx4 >> 7;                        // 128 float4 per row
    float n  = *n_sum;
    float smoothed = (out_ecs[row] + EPS_) / (n + KSZ_ * EPS_) * n;
    float inv = 1.0f / smoothed;
    size_t e = (size_t)idx4 * 4;
    float4 wv = *(const float4*)&ema_w[e];
    float4 dv = *(const float4*)&dw[e];
    float w0 = EMA_DECAY_ * wv.x + (1.0f - EMA_DECAY_) * dv.x;
    float w1 = EMA_DECAY_ * wv.y + (1.0f - EMA_DECAY_) * dv.y;
    float w2 = EMA_DECAY_ * wv.z + (1.0f - EMA_DECAY_) * dv.z;
    float w3 = EMA_DECAY_ * wv.w + (1.0f - EMA_DECAY_) * dv.w;
    out_emaw[e + 0] = w0; out_emaw[e + 1] = w1;
    out_emaw[e + 2] = w2; out_emaw[e + 3] = w3;
    out_K[e + 0] = w0 * inv; out_K[e + 1] = w1 * inv;
    out_K[e + 2] = w2 * inv; out_K[e + 3] = w3 * inv;
    if (idx4 == 0) *out_loss = *loss_sum * (1.0f / 16777216.0f);
}

// ---------------------------------------------------------------------------
// Workspace layout (float offsets):
//   0        Kt2        [4096]
//   4096     bestd      [32768*8]
//   266240   bestidx    [32768*8] (int)
//   528384   counts     [4096]      <- zeroed each launch
//   532480   dw         [4096*512]  <- zeroed
//   2629632  loss_sum   [1]         <- zeroed
//   2629633  n_sum      [1]         <- zeroed
// total 2629634 floats (~10.5 MB)
// ---------------------------------------------------------------------------
extern "C" void kernel_launch(void* const* d_in, const int* in_sizes, int n_in,
                              void* d_out, int out_size, void* d_ws, size_t ws_size,
                              hipStream_t stream) {
    const float* f     = (const float*)d_in[0];
    const float* K     = (const float*)d_in[1];
    const float* ecs   = (const float*)d_in[2];
    const float* ema_w = (const float*)d_in[3];

    float* ws       = (float*)d_ws;
    float* Kt2      = ws;
    float* bestd    = ws + 4096;
    int*   bestidx  = (int*)(ws + 266240);
    float* counts   = ws + 528384;
    float* dw       = ws + 532480;
    float* loss_sum = ws + 2629632;
    float* n_sum    = ws + 2629633;

    float* out      = (float*)d_out;
    float* out_fipm = out;                    // 16777216
    float* out_loss = out + 16777216;         // 1
    float* out_K    = out + 16777217;         // 2097152
    float* out_ecs  = out + 18874369;         // 4096
    float* out_emaw = out + 18878465;         // 2097152

    // zero accumulators: counts + dw + loss + n (contiguous)
    hipMemsetAsync(counts, 0, (size_t)(4096 + 2097152 + 2) * sizeof(float), stream);

    kt2_kernel<<<KSZ_ * 64 / 256, 256, 0, stream>>>(K, Kt2);

    dim3 grid(NROWS / BM, CSPLIT);
    argmin_kernel<<<grid, 256, 0, stream>>>(f, K, Kt2, bestd, bestidx);

    gather_kernel<<<NROWS * 64 / 256, 256, 0, stream>>>(
        f, K, bestd, bestidx, out_fipm, loss_sum, counts, dw);

    ecs_kernel<<<KSZ_ / 256, 256, 0, stream>>>(ecs, counts, out_ecs, n_sum);

    final_kernel<<<(KSZ_ * DDIM / 4) / 256, 256, 0, stream>>>(
        ema_w, dw, out_ecs, n_sum, loss_sum, out_K, out_emaw, out_loss);
}

// Round 2
// 1007.649 us; speedup vs baseline: 2.7201x; 1.1006x over previous
//
#include <hip/hip_runtime.h>
#include <hip/hip_bf16.h>

// Problem constants
#define NROWS 32768
#define DDIM  512
#define KSZ_  4096
#define EMA_DECAY_ 0.99f
#define EPS_ 1e-5f

// MFMA GEMM-argmin tiling
#define BM 128            // rows of f per block
#define BN 128            // codebook cols per chunk
#define NCHUNK 4          // column chunks per block
#define CSPLIT 8          // N-dim split across blocks (grid.y)
#define BKB 64            // bf16 k per K-step (2 MFMA k-halves of 32)
// LDS tile: [128 rows][64 bf16] linear (128B rows), swizzle baked into the
// global layout: store[r][slot] = data[r][slot ^ (r&7)], slot = 16B granule.

typedef float f32x4 __attribute__((ext_vector_type(4)));
typedef __bf16 bf16x8 __attribute__((ext_vector_type(8)));

// ---------------------------------------------------------------------------
// global -> LDS 16B async copy (per-lane global addr, wave-uniform LDS base)
// ---------------------------------------------------------------------------
__device__ __forceinline__ void g2lds16(const __bf16* g, __bf16* l) {
    __builtin_amdgcn_global_load_lds(
        (const __attribute__((address_space(1))) void*)g,
        (__attribute__((address_space(3))) void*)l, 16, 0, 0);
}

// ---------------------------------------------------------------------------
// split fp32 -> bf16 hi + bf16 lo (hi = RNE(x), lo = RNE(x - hi))
// ---------------------------------------------------------------------------
__device__ __forceinline__ void cvt8(const float4 x0, const float4 x1,
                                     bf16x8& h, bf16x8& l) {
    float xs[8] = {x0.x, x0.y, x0.z, x0.w, x1.x, x1.y, x1.z, x1.w};
#pragma unroll
    for (int j = 0; j < 8; j++) {
        __bf16 hj = (__bf16)xs[j];
        h[j] = hj;
        l[j] = (__bf16)(xs[j] - (float)hj);
    }
}

// ---------------------------------------------------------------------------
// Kernel 0: convert fp32 [nrb*128][512] -> bf16 hi/lo arrays in swizzled
// LDS-tile order: granule g = ((rb*8 + ks)*128 + r)*8 + s holds source
// elements k = ks*64 + (s ^ (r&7))*8 .. +8 of row rb*128+r.
// ---------------------------------------------------------------------------
__global__ __launch_bounds__(256) void convert_kernel(
    const float* __restrict__ src,
    __bf16* __restrict__ hi, __bf16* __restrict__ lo) {
    int g  = blockIdx.x * 256 + threadIdx.x;
    int s  = g & 7;
    int r  = (g >> 3) & 127;
    int ks = (g >> 10) & 7;
    int rb = g >> 13;
    int srck = ks * 64 + ((s ^ (r & 7)) * 8);
    const float* p = src + (size_t)(rb * 128 + r) * DDIM + srck;
    float4 x0 = *(const float4*)p;
    float4 x1 = *(const float4*)(p + 4);
    bf16x8 h, l;
    cvt8(x0, x1, h, l);
    *(bf16x8*)(hi + (size_t)g * 8) = h;
    *(bf16x8*)(lo + (size_t)g * 8) = l;
}

// ---------------------------------------------------------------------------
// Kernel 1: Kt2[j] = sum_d K[j][d]^2   (one wave per row)
// ---------------------------------------------------------------------------
__global__ __launch_bounds__(256) void kt2_kernel(const float* __restrict__ K,
                                                  float* __restrict__ Kt2) {
    int gid  = blockIdx.x * 256 + threadIdx.x;
    int row  = gid >> 6;
    int lane = threadIdx.x & 63;
    const float* kr = K + (size_t)row * DDIM;
    float s = 0.f;
#pragma unroll
    for (int u = 0; u < 2; u++) {
        float4 v = *(const float4*)&kr[u * 256 + lane * 4];
        s += v.x * v.x + v.y * v.y + v.z * v.z + v.w * v.w;
    }
#pragma unroll
    for (int off = 1; off < 64; off <<= 1) s += __shfl_xor(s, off, 64);
    if (lane == 0) Kt2[row] = s;
}

// ---------------------------------------------------------------------------
// Kernel 2: fused bf16x3 MFMA GEMM + argmin over pre-converted tiles.
// score = 0.5*|K[j]|^2 - f.K[j]; f.K = fh.Kh + fh.Kl + fl.Kh.
// Block: BM rows x (BN*NCHUNK) cols; grid.y = CSPLIT splits of the N dim.
// Staging via global_load_lds (16B), swizzle pre-baked in global layout.
// ---------------------------------------------------------------------------
__global__ __launch_bounds__(256, 2) void argmin_kernel(
    const __bf16* __restrict__ fh, const __bf16* __restrict__ fl,
    const __bf16* __restrict__ kh, const __bf16* __restrict__ kl,
    const float* __restrict__ Kt2,
    float* __restrict__ bestd, int* __restrict__ bestidx) {

    __shared__ __align__(16) __bf16 Ah[BM * BKB];
    __shared__ __align__(16) __bf16 Al[BM * BKB];
    __shared__ __align__(16) __bf16 Bh[BN * BKB];
    __shared__ __align__(16) __bf16 Bl[BN * BKB];
    __shared__ float redD[2][BM];
    __shared__ int   redI[2][BM];

    const int tid  = threadIdx.x;
    const int lane = tid & 63;
    const int w    = tid >> 6;
    const int wr   = w >> 1;       // wave row (0..1)
    const int wc   = w & 1;        // wave col (0..1)
    const int l15  = lane & 15;
    const int l4   = lane >> 4;
    const int rb   = blockIdx.x;   // row block (0..255)
    const int split = blockIdx.y;  // 0..7

    float best[16];
    int   bidx[16];
#pragma unroll
    for (int i = 0; i < 16; i++) { best[i] = 3.4e38f; bidx[i] = 0x7fffffff; }

    for (int chunk = 0; chunk < NCHUNK; ++chunk) {
        const int cb = split * NCHUNK + chunk;   // col block (0..31)
        const int c0 = cb * BN;
        f32x4 acc[4][4];
#pragma unroll
        for (int m = 0; m < 4; m++)
#pragma unroll
            for (int n = 0; n < 4; n++)
                acc[m][n] = (f32x4){0.f, 0.f, 0.f, 0.f};

        for (int ks = 0; ks < DDIM / BKB; ++ks) {
            const __bf16* tAh = fh + (size_t)(rb * 8 + ks) * (BM * BKB);
            const __bf16* tAl = fl + (size_t)(rb * 8 + ks) * (BM * BKB);
            const __bf16* tBh = kh + (size_t)(cb * 8 + ks) * (BN * BKB);
            const __bf16* tBl = kl + (size_t)(cb * 8 + ks) * (BN * BKB);
            __syncthreads();
            // stage 4 tiles x 16KB; each thread 4 granules of 16B per tile
#pragma unroll
            for (int i = 0; i < 4; i++) {
                const int gg  = i * 256 + tid;            // per-lane granule
                const int ub  = (i * 256 + w * 64) * 8;   // wave-uniform base (shorts)
                g2lds16(tAh + (size_t)gg * 8, Ah + ub);
                g2lds16(tAl + (size_t)gg * 8, Al + ub);
                g2lds16(tBh + (size_t)gg * 8, Bh + ub);
                g2lds16(tBl + (size_t)gg * 8, Bl + ub);
            }
            __syncthreads();

#pragma unroll
            for (int h = 0; h < 2; ++h) {
                bf16x8 av[4], alv[4], bv[4], blv[4];
#pragma unroll
                for (int m = 0; m < 4; m++) {
                    int row  = wr * 64 + m * 16 + l15;
                    int slot = (h * 4 + l4) ^ (l15 & 7);
                    int off  = row * BKB + slot * 8;
                    av[m]  = *(const bf16x8*)&Ah[off];
                    alv[m] = *(const bf16x8*)&Al[off];
                }
#pragma unroll
                for (int n = 0; n < 4; n++) {
                    int row  = wc * 64 + n * 16 + l15;
                    int slot = (h * 4 + l4) ^ (l15 & 7);
                    int off  = row * BKB + slot * 8;
                    bv[n]  = *(const bf16x8*)&Bh[off];
                    blv[n] = *(const bf16x8*)&Bl[off];
                }
#pragma unroll
                for (int m = 0; m < 4; m++)
#pragma unroll
                    for (int n = 0; n < 4; n++)
                        acc[m][n] = __builtin_amdgcn_mfma_f32_16x16x32_bf16(av[m], bv[n], acc[m][n], 0, 0, 0);
#pragma unroll
                for (int m = 0; m < 4; m++)
#pragma unroll
                    for (int n = 0; n < 4; n++)
                        acc[m][n] = __builtin_amdgcn_mfma_f32_16x16x32_bf16(av[m], blv[n], acc[m][n], 0, 0, 0);
#pragma unroll
                for (int m = 0; m < 4; m++)
#pragma unroll
                    for (int n = 0; n < 4; n++)
                        acc[m][n] = __builtin_amdgcn_mfma_f32_16x16x32_bf16(alv[m], bv[n], acc[m][n], 0, 0, 0);
            }
        }

        // chunk epilogue: argmin update. acc[m][n][q] is output
        // row = wr*64 + m*16 + l4*4 + q, col = wc*64 + n*16 + l15.
        float kt2c[4];
#pragma unroll
        for (int n = 0; n < 4; n++) kt2c[n] = Kt2[c0 + wc * 64 + n * 16 + l15];
#pragma unroll
        for (int m = 0; m < 4; m++)
#pragma unroll
            for (int q = 0; q < 4; q++) {
                float d = 3.4e38f; int bi = 0x7fffffff;
#pragma unroll
                for (int n = 0; n < 4; n++) {
                    float s = 0.5f * kt2c[n] - acc[m][n][q];
                    int col = c0 + wc * 64 + n * 16 + l15;
                    if (s < d || (s == d && col < bi)) { d = s; bi = col; }
                }
                int i16 = m * 4 + q;
                if (d < best[i16] || (d == best[i16] && bi < bidx[i16])) {
                    best[i16] = d; bidx[i16] = bi;
                }
            }
    }

    // cross-lane reduce within 16-lane groups (same rows), then cross-wave
#pragma unroll
    for (int i = 0; i < 16; i++) {
        float d = best[i]; int bi = bidx[i];
#pragma unroll
        for (int off = 1; off < 16; off <<= 1) {
            float od = __shfl_xor(d, off, 64);
            int   oi = __shfl_xor(bi, off, 64);
            if (od < d || (od == d && oi < bi)) { d = od; bi = oi; }
        }
        if (l15 == 0) {
            int m = i >> 2, q = i & 3;
            int rl = wr * 64 + m * 16 + l4 * 4 + q;
            redD[wc][rl] = d;
            redI[wc][rl] = bi;
        }
    }
    __syncthreads();
    if (tid < BM) {
        float d0 = redD[0][tid], d1 = redD[1][tid];
        int   i0 = redI[0][tid], i1 = redI[1][tid];
        if (d1 < d0 || (d1 == d0 && i1 < i0)) { d0 = d1; i0 = i1; }
        bestd[(size_t)(rb * BM + tid) * CSPLIT + split]   = d0;
        bestidx[(size_t)(rb * BM + tid) * CSPLIT + split] = i0;
    }
}

// ---------------------------------------------------------------------------
// Kernel 3: per-row split-reduce, gather K[k1] -> f_ipmlm, loss partial,
// scatter counts/dw via atomics. One wave per row.
// ---------------------------------------------------------------------------
__global__ __launch_bounds__(256) void gather_kernel(
    const float* __restrict__ f, const float* __restrict__ K,
    const float* __restrict__ bestd, const int* __restrict__ bestidx,
    float* __restrict__ out_fipm, float* __restrict__ loss_sum,
    float* __restrict__ counts, float* __restrict__ dw) {
    int gid  = blockIdx.x * 256 + threadIdx.x;
    int row  = gid >> 6;
    int lane = threadIdx.x & 63;

    float d = bestd[(size_t)row * CSPLIT];
    int  bi = bestidx[(size_t)row * CSPLIT];
#pragma unroll
    for (int s = 1; s < CSPLIT; s++) {
        float od = bestd[(size_t)row * CSPLIT + s];
        int   oi = bestidx[(size_t)row * CSPLIT + s];
        if (od < d || (od == d && oi < bi)) { d = od; bi = oi; }
    }

    const float* frow = f + (size_t)row * DDIM;
    const float* krow = K + (size_t)bi * DDIM;
    float lsum = 0.f;
#pragma unroll
    for (int u = 0; u < 2; u++) {
        int off = u * 256 + lane * 4;
        float4 fv = *(const float4*)&frow[off];
        float4 kv = *(const float4*)&krow[off];
        *(float4*)&out_fipm[(size_t)row * DDIM + off] = kv;
        float dx = kv.x - fv.x, dy = kv.y - fv.y, dz = kv.z - fv.z, dwv = kv.w - fv.w;
        lsum += dx * dx + dy * dy + dz * dz + dwv * dwv;
        float* dst = &dw[(size_t)bi * DDIM + off];
        atomicAdd(dst + 0, fv.x);
        atomicAdd(dst + 1, fv.y);
        atomicAdd(dst + 2, fv.z);
        atomicAdd(dst + 3, fv.w);
    }
#pragma unroll
    for (int off = 1; off < 64; off <<= 1) lsum += __shfl_xor(lsum, off, 64);
    if (lane == 0) {
        atomicAdd(loss_sum, lsum);
        atomicAdd(&counts[bi], 1.0f);
    }
}

// ---------------------------------------------------------------------------
// Kernel 4: new_ecs = 0.99*ecs + 0.01*counts; n = sum(new_ecs)
// ---------------------------------------------------------------------------
__global__ __launch_bounds__(256) void ecs_kernel(
    const float* __restrict__ ecs_in, const float* __restrict__ counts,
    float* __restrict__ out_ecs, float* __restrict__ n_sum) {
    int i = blockIdx.x * 256 + threadIdx.x;
    float v = ecs_in[i] * EMA_DECAY_ + (1.0f - EMA_DECAY_) * counts[i];
    out_ecs[i] = v;
    float s = v;
#pragma unroll
    for (int off = 1; off < 64; off <<= 1) s += __shfl_xor(s, off, 64);
    if ((threadIdx.x & 63) == 0) atomicAdd(n_sum, s);
}

// ---------------------------------------------------------------------------
// Kernel 5: new_ema_w = 0.99*ema_w + 0.01*dw; new_K = new_ema_w / smoothed
// ---------------------------------------------------------------------------
__global__ __launch_bounds__(256) void final_kernel(
    const float* __restrict__ ema_w, const float* __restrict__ dw,
    const float* __restrict__ out_ecs, const float* __restrict__ n_sum,
    const float* __restrict__ loss_sum,
    float* __restrict__ out_K, float* __restrict__ out_emaw,
    float* __restrict__ out_loss) {
    int idx4 = blockIdx.x * 256 + threadIdx.x;   // 0..524287 (float4 granules)
    int row  = idx4 >> 7;                        // 128 float4 per row
    float n  = *n_sum;
    float smoothed = (out_ecs[row] + EPS_) / (n + KSZ_ * EPS_) * n;
    float inv = 1.0f / smoothed;
    size_t e = (size_t)idx4 * 4;
    float4 wv = *(const float4*)&ema_w[e];
    float4 dv = *(const float4*)&dw[e];
    float w0 = EMA_DECAY_ * wv.x + (1.0f - EMA_DECAY_) * dv.x;
    float w1 = EMA_DECAY_ * wv.y + (1.0f - EMA_DECAY_) * dv.y;
    float w2 = EMA_DECAY_ * wv.z + (1.0f - EMA_DECAY_) * dv.z;
    float w3 = EMA_DECAY_ * wv.w + (1.0f - EMA_DECAY_) * dv.w;
    out_emaw[e + 0] = w0; out_emaw[e + 1] = w1;
    out_emaw[e + 2] = w2; out_emaw[e + 3] = w3;
    out_K[e + 0] = w0 * inv; out_K[e + 1] = w1 * inv;
    out_K[e + 2] = w2 * inv; out_K[e + 3] = w3 * inv;
    if (idx4 == 0) *out_loss = *loss_sum * (1.0f / 16777216.0f);
}

// ---------------------------------------------------------------------------
// Workspace layout (float offsets):
//   0         Kt2       [4096]
//   4096      bestd     [32768*8]
//   266240    bestidx   [32768*8] (int)
//   528384    counts    [4096]       <- zeroed each launch
//   532480    dw        [4096*512]   <- zeroed
//   2629632   loss_sum  [1]          <- zeroed
//   2629633   n_sum     [1]          <- zeroed
//   2629636   fh_swz    [32768*512 bf16 = 8388608 floats]
//   11018244  fl_swz    [8388608 floats]
//   19406852  kh_swz    [4096*512 bf16 = 1048576 floats]
//   20455428  kl_swz    [1048576 floats]
// total 21504004 floats (~86 MB)
// ---------------------------------------------------------------------------
extern "C" void kernel_launch(void* const* d_in, const int* in_sizes, int n_in,
                              void* d_out, int out_size, void* d_ws, size_t ws_size,
                              hipStream_t stream) {
    const float* f     = (const float*)d_in[0];
    const float* K     = (const float*)d_in[1];
    const float* ecs   = (const float*)d_in[2];
    const float* ema_w = (const float*)d_in[3];

    float* ws       = (float*)d_ws;
    float* Kt2      = ws;
    float* bestd    = ws + 4096;
    int*   bestidx  = (int*)(ws + 266240);
    float* counts   = ws + 528384;
    float* dw       = ws + 532480;
    float* loss_sum = ws + 2629632;
    float* n_sum    = ws + 2629633;
    __bf16* fh      = (__bf16*)(ws + 2629636);
    __bf16* fl      = (__bf16*)(ws + 11018244);
    __bf16* kh      = (__bf16*)(ws + 19406852);
    __bf16* kl      = (__bf16*)(ws + 20455428);

    float* out      = (float*)d_out;
    float* out_fipm = out;                    // 16777216
    float* out_loss = out + 16777216;         // 1
    float* out_K    = out + 16777217;         // 2097152
    float* out_ecs  = out + 18874369;         // 4096
    float* out_emaw = out + 18878465;         // 2097152

    // zero accumulators: counts + dw + loss + n (contiguous)
    hipMemsetAsync(counts, 0, (size_t)(4096 + 2097152 + 2) * sizeof(float), stream);

    // pre-convert f and K to swizzled bf16 hi/lo tiles
    convert_kernel<<<NROWS * DDIM / 8 / 256, 256, 0, stream>>>(f, fh, fl);
    convert_kernel<<<KSZ_ * DDIM / 8 / 256, 256, 0, stream>>>(K, kh, kl);

    kt2_kernel<<<KSZ_ * 64 / 256, 256, 0, stream>>>(K, Kt2);

    dim3 grid(NROWS / BM, CSPLIT);
    argmin_kernel<<<grid, 256, 0, stream>>>(fh, fl, kh, kl, Kt2, bestd, bestidx);

    gather_kernel<<<NROWS * 64 / 256, 256, 0, stream>>>(
        f, K, bestd, bestidx, out_fipm, loss_sum, counts, dw);

    ecs_kernel<<<KSZ_ / 256, 256, 0, stream>>>(ecs, counts, out_ecs, n_sum);

    final_kernel<<<(KSZ_ * DDIM / 4) / 256, 256, 0, stream>>>(
        ema_w, dw, out_ecs, n_sum, loss_sum, out_K, out_emaw, out_loss);
}

// Round 3
// 695.247 us; speedup vs baseline: 3.9423x; 1.4493x over previous
//
#include <hip/hip_runtime.h>
#include <hip/hip_bf16.h>

// Problem constants
#define NROWS 32768
#define DDIM  512
#define KSZ_  4096
#define EMA_DECAY_ 0.99f
#define EPS_ 1e-5f

// MFMA GEMM-argmin tiling
#define BM 128            // rows of f per block
#define BN 128            // codebook cols per chunk
#define NCHUNK 4          // column chunks per block
#define CSPLIT 8          // N-dim split across blocks (grid.y)
#define BKB 64            // bf16 k per K-step (2 MFMA k-halves of 32)
// LDS tile: [128 rows][64 bf16] linear (128B rows), swizzle baked into the
// global layout: store[r][slot] = data[r][slot ^ (r&7)], slot = 16B granule.

typedef float f32x4 __attribute__((ext_vector_type(4)));
typedef __bf16 bf16x8 __attribute__((ext_vector_type(8)));

// ---------------------------------------------------------------------------
// global -> LDS 16B async copy (per-lane global addr, wave-uniform LDS base)
// ---------------------------------------------------------------------------
__device__ __forceinline__ void g2lds16(const __bf16* g, __bf16* l) {
    __builtin_amdgcn_global_load_lds(
        (const __attribute__((address_space(1))) void*)g,
        (__attribute__((address_space(3))) void*)l, 16, 0, 0);
}

// ---------------------------------------------------------------------------
// split fp32 -> bf16 hi + bf16 lo (hi = RNE(x), lo = RNE(x - hi))
// ---------------------------------------------------------------------------
__device__ __forceinline__ void cvt8(const float4 x0, const float4 x1,
                                     bf16x8& h, bf16x8& l) {
    float xs[8] = {x0.x, x0.y, x0.z, x0.w, x1.x, x1.y, x1.z, x1.w};
#pragma unroll
    for (int j = 0; j < 8; j++) {
        __bf16 hj = (__bf16)xs[j];
        h[j] = hj;
        l[j] = (__bf16)(xs[j] - (float)hj);
    }
}

// ---------------------------------------------------------------------------
// Kernel 0: convert fp32 [nrb*128][512] -> bf16 hi/lo arrays in swizzled
// LDS-tile order: granule g = ((rb*8 + ks)*128 + r)*8 + s holds source
// elements k = ks*64 + (s ^ (r&7))*8 .. +8 of row rb*128+r.
// ---------------------------------------------------------------------------
__global__ __launch_bounds__(256) void convert_kernel(
    const float* __restrict__ src,
    __bf16* __restrict__ hi, __bf16* __restrict__ lo) {
    int g  = blockIdx.x * 256 + threadIdx.x;
    int s  = g & 7;
    int r  = (g >> 3) & 127;
    int ks = (g >> 10) & 7;
    int rb = g >> 13;
    int srck = ks * 64 + ((s ^ (r & 7)) * 8);
    const float* p = src + (size_t)(rb * 128 + r) * DDIM + srck;
    float4 x0 = *(const float4*)p;
    float4 x1 = *(const float4*)(p + 4);
    bf16x8 h, l;
    cvt8(x0, x1, h, l);
    *(bf16x8*)(hi + (size_t)g * 8) = h;
    *(bf16x8*)(lo + (size_t)g * 8) = l;
}

// ---------------------------------------------------------------------------
// Kernel 1: Kt2[j] = sum_d K[j][d]^2   (one wave per row)
// ---------------------------------------------------------------------------
__global__ __launch_bounds__(256) void kt2_kernel(const float* __restrict__ K,
                                                  float* __restrict__ Kt2) {
    int gid  = blockIdx.x * 256 + threadIdx.x;
    int row  = gid >> 6;
    int lane = threadIdx.x & 63;
    const float* kr = K + (size_t)row * DDIM;
    float s = 0.f;
#pragma unroll
    for (int u = 0; u < 2; u++) {
        float4 v = *(const float4*)&kr[u * 256 + lane * 4];
        s += v.x * v.x + v.y * v.y + v.z * v.z + v.w * v.w;
    }
#pragma unroll
    for (int off = 1; off < 64; off <<= 1) s += __shfl_xor(s, off, 64);
    if (lane == 0) Kt2[row] = s;
}

// ---------------------------------------------------------------------------
// Kernel 2: fused bf16x3 MFMA GEMM + argmin over pre-converted tiles.
// score = 0.5*|K[j]|^2 - f.K[j]; f.K = fh.Kh + fh.Kl + fl.Kh.
// ---------------------------------------------------------------------------
__global__ __launch_bounds__(256, 2) void argmin_kernel(
    const __bf16* __restrict__ fh, const __bf16* __restrict__ fl,
    const __bf16* __restrict__ kh, const __bf16* __restrict__ kl,
    const float* __restrict__ Kt2,
    float* __restrict__ bestd, int* __restrict__ bestidx) {

    __shared__ __align__(16) __bf16 Ah[BM * BKB];
    __shared__ __align__(16) __bf16 Al[BM * BKB];
    __shared__ __align__(16) __bf16 Bh[BN * BKB];
    __shared__ __align__(16) __bf16 Bl[BN * BKB];
    __shared__ float redD[2][BM];
    __shared__ int   redI[2][BM];

    const int tid  = threadIdx.x;
    const int lane = tid & 63;
    const int w    = tid >> 6;
    const int wr   = w >> 1;       // wave row (0..1)
    const int wc   = w & 1;        // wave col (0..1)
    const int l15  = lane & 15;
    const int l4   = lane >> 4;
    const int rb   = blockIdx.x;   // row block (0..255)
    const int split = blockIdx.y;  // 0..7

    float best[16];
    int   bidx[16];
#pragma unroll
    for (int i = 0; i < 16; i++) { best[i] = 3.4e38f; bidx[i] = 0x7fffffff; }

    for (int chunk = 0; chunk < NCHUNK; ++chunk) {
        const int cb = split * NCHUNK + chunk;   // col block (0..31)
        const int c0 = cb * BN;
        f32x4 acc[4][4];
#pragma unroll
        for (int m = 0; m < 4; m++)
#pragma unroll
            for (int n = 0; n < 4; n++)
                acc[m][n] = (f32x4){0.f, 0.f, 0.f, 0.f};

        for (int ks = 0; ks < DDIM / BKB; ++ks) {
            const __bf16* tAh = fh + (size_t)(rb * 8 + ks) * (BM * BKB);
            const __bf16* tAl = fl + (size_t)(rb * 8 + ks) * (BM * BKB);
            const __bf16* tBh = kh + (size_t)(cb * 8 + ks) * (BN * BKB);
            const __bf16* tBl = kl + (size_t)(cb * 8 + ks) * (BN * BKB);
            __syncthreads();
            // stage 4 tiles x 16KB; each thread 4 granules of 16B per tile
#pragma unroll
            for (int i = 0; i < 4; i++) {
                const int gg  = i * 256 + tid;            // per-lane granule
                const int ub  = (i * 256 + w * 64) * 8;   // wave-uniform base (shorts)
                g2lds16(tAh + (size_t)gg * 8, Ah + ub);
                g2lds16(tAl + (size_t)gg * 8, Al + ub);
                g2lds16(tBh + (size_t)gg * 8, Bh + ub);
                g2lds16(tBl + (size_t)gg * 8, Bl + ub);
            }
            __syncthreads();

#pragma unroll
            for (int h = 0; h < 2; ++h) {
                bf16x8 av[4], alv[4], bv[4], blv[4];
#pragma unroll
                for (int m = 0; m < 4; m++) {
                    int row  = wr * 64 + m * 16 + l15;
                    int slot = (h * 4 + l4) ^ (l15 & 7);
                    int off  = row * BKB + slot * 8;
                    av[m]  = *(const bf16x8*)&Ah[off];
                    alv[m] = *(const bf16x8*)&Al[off];
                }
#pragma unroll
                for (int n = 0; n < 4; n++) {
                    int row  = wc * 64 + n * 16 + l15;
                    int slot = (h * 4 + l4) ^ (l15 & 7);
                    int off  = row * BKB + slot * 8;
                    bv[n]  = *(const bf16x8*)&Bh[off];
                    blv[n] = *(const bf16x8*)&Bl[off];
                }
#pragma unroll
                for (int m = 0; m < 4; m++)
#pragma unroll
                    for (int n = 0; n < 4; n++)
                        acc[m][n] = __builtin_amdgcn_mfma_f32_16x16x32_bf16(av[m], bv[n], acc[m][n], 0, 0, 0);
#pragma unroll
                for (int m = 0; m < 4; m++)
#pragma unroll
                    for (int n = 0; n < 4; n++)
                        acc[m][n] = __builtin_amdgcn_mfma_f32_16x16x32_bf16(av[m], blv[n], acc[m][n], 0, 0, 0);
#pragma unroll
                for (int m = 0; m < 4; m++)
#pragma unroll
                    for (int n = 0; n < 4; n++)
                        acc[m][n] = __builtin_amdgcn_mfma_f32_16x16x32_bf16(alv[m], bv[n], acc[m][n], 0, 0, 0);
            }
        }

        // chunk epilogue: argmin update. acc[m][n][q] is output
        // row = wr*64 + m*16 + l4*4 + q, col = wc*64 + n*16 + l15.
        float kt2c[4];
#pragma unroll
        for (int n = 0; n < 4; n++) kt2c[n] = Kt2[c0 + wc * 64 + n * 16 + l15];
#pragma unroll
        for (int m = 0; m < 4; m++)
#pragma unroll
            for (int q = 0; q < 4; q++) {
                float d = 3.4e38f; int bi = 0x7fffffff;
#pragma unroll
                for (int n = 0; n < 4; n++) {
                    float s = 0.5f * kt2c[n] - acc[m][n][q];
                    int col = c0 + wc * 64 + n * 16 + l15;
                    if (s < d || (s == d && col < bi)) { d = s; bi = col; }
                }
                int i16 = m * 4 + q;
                if (d < best[i16] || (d == best[i16] && bi < bidx[i16])) {
                    best[i16] = d; bidx[i16] = bi;
                }
            }
    }

    // cross-lane reduce within 16-lane groups (same rows), then cross-wave
#pragma unroll
    for (int i = 0; i < 16; i++) {
        float d = best[i]; int bi = bidx[i];
#pragma unroll
        for (int off = 1; off < 16; off <<= 1) {
            float od = __shfl_xor(d, off, 64);
            int   oi = __shfl_xor(bi, off, 64);
            if (od < d || (od == d && oi < bi)) { d = od; bi = oi; }
        }
        if (l15 == 0) {
            int m = i >> 2, q = i & 3;
            int rl = wr * 64 + m * 16 + l4 * 4 + q;
            redD[wc][rl] = d;
            redI[wc][rl] = bi;
        }
    }
    __syncthreads();
    if (tid < BM) {
        float d0 = redD[0][tid], d1 = redD[1][tid];
        int   i0 = redI[0][tid], i1 = redI[1][tid];
        if (d1 < d0 || (d1 == d0 && i1 < i0)) { d0 = d1; i0 = i1; }
        bestd[(size_t)(rb * BM + tid) * CSPLIT + split]   = d0;
        bestidx[(size_t)(rb * BM + tid) * CSPLIT + split] = i0;
    }
}

// ---------------------------------------------------------------------------
// Kernel 3a: per-row split reduce -> k1[row]; count clusters (int atomics,
// spread over 4096 addresses).
// ---------------------------------------------------------------------------
__global__ __launch_bounds__(256) void reduce_kernel(
    const float* __restrict__ bestd, const int* __restrict__ bestidx,
    int* __restrict__ k1, int* __restrict__ cnt) {
    int row = blockIdx.x * 256 + threadIdx.x;
    float4 d0 = *(const float4*)&bestd[(size_t)row * CSPLIT];
    float4 d1 = *(const float4*)&bestd[(size_t)row * CSPLIT + 4];
    int4   i0 = *(const int4*)&bestidx[(size_t)row * CSPLIT];
    int4   i1 = *(const int4*)&bestidx[(size_t)row * CSPLIT + 4];
    float ds[8] = {d0.x, d0.y, d0.z, d0.w, d1.x, d1.y, d1.z, d1.w};
    int   is[8] = {i0.x, i0.y, i0.z, i0.w, i1.x, i1.y, i1.z, i1.w};
    float d = ds[0]; int bi = is[0];
#pragma unroll
    for (int s = 1; s < 8; s++)
        if (ds[s] < d || (ds[s] == d && is[s] < bi)) { d = ds[s]; bi = is[s]; }
    k1[row] = bi;
    atomicAdd(&cnt[bi], 1);
}

// ---------------------------------------------------------------------------
// Kernel 3b: exclusive prefix sum of cnt[4096] -> offs[4096]. One block.
// ---------------------------------------------------------------------------
__global__ __launch_bounds__(256) void scan_kernel(
    const int* __restrict__ cnt, int* __restrict__ offs) {
    __shared__ int sums[256];
    int t = threadIdx.x;
    int local[16];
    int s = 0;
#pragma unroll
    for (int i = 0; i < 16; i++) { local[i] = cnt[t * 16 + i]; s += local[i]; }
    sums[t] = s;
    __syncthreads();
    for (int off = 1; off < 256; off <<= 1) {
        int v = (t >= off) ? sums[t - off] : 0;
        __syncthreads();
        sums[t] += v;
        __syncthreads();
    }
    int run = sums[t] - s;   // exclusive
#pragma unroll
    for (int i = 0; i < 16; i++) { offs[t * 16 + i] = run; run += local[i]; }
}

// ---------------------------------------------------------------------------
// Kernel 3c: scatter rows into cluster buckets.
// ---------------------------------------------------------------------------
__global__ __launch_bounds__(256) void scatter_kernel(
    const int* __restrict__ k1, const int* __restrict__ offs,
    int* __restrict__ cursor, int* __restrict__ bucket) {
    int row = blockIdx.x * 256 + threadIdx.x;
    int bi = k1[row];
    int pos = atomicAdd(&cursor[bi], 1);
    bucket[offs[bi] + pos] = row;
}

// ---------------------------------------------------------------------------
// Kernel 3d: gather K[k1] -> f_ipmlm + loss. 8 rows per wave, one loss
// atomic per block.
// ---------------------------------------------------------------------------
__global__ __launch_bounds__(256) void gather_kernel(
    const float* __restrict__ f, const float* __restrict__ K,
    const int* __restrict__ k1,
    float* __restrict__ out_fipm, float* __restrict__ loss_sum) {
    __shared__ float ls[4];
    int tid  = threadIdx.x;
    int wid  = (blockIdx.x * 256 + tid) >> 6;   // wave id, 0..4095
    int lane = tid & 63;
    float lsum = 0.f;
#pragma unroll
    for (int rr = 0; rr < 8; rr++) {
        int row = wid * 8 + rr;
        int bi  = k1[row];
        const float* frow = f + (size_t)row * DDIM;
        const float* krow = K + (size_t)bi * DDIM;
#pragma unroll
        for (int u = 0; u < 2; u++) {
            int off = u * 256 + lane * 4;
            float4 fv = *(const float4*)&frow[off];
            float4 kv = *(const float4*)&krow[off];
            *(float4*)&out_fipm[(size_t)row * DDIM + off] = kv;
            float dx = kv.x - fv.x, dy = kv.y - fv.y;
            float dz = kv.z - fv.z, dwv = kv.w - fv.w;
            lsum += dx * dx + dy * dy + dz * dz + dwv * dwv;
        }
    }
#pragma unroll
    for (int off = 1; off < 64; off <<= 1) lsum += __shfl_xor(lsum, off, 64);
    if (lane == 0) ls[tid >> 6] = lsum;
    __syncthreads();
    if (tid == 0) atomicAdd(loss_sum, ls[0] + ls[1] + ls[2] + ls[3]);
}

// ---------------------------------------------------------------------------
// Kernel 3e: dw[j] = sum of f rows in bucket j. One block per cluster,
// no atomics. Thread t owns floats [2t, 2t+1] of the 512-dim row.
// ---------------------------------------------------------------------------
__global__ __launch_bounds__(256) void dw_kernel(
    const float* __restrict__ f, const int* __restrict__ offs,
    const int* __restrict__ cnt, const int* __restrict__ bucket,
    float* __restrict__ dw) {
    int j = blockIdx.x;
    int t = threadIdx.x;
    int beg = offs[j];
    int c   = cnt[j];
    float2 acc = {0.f, 0.f};
    int i = 0;
    for (; i + 1 < c; i += 2) {
        int r0 = bucket[beg + i];
        int r1 = bucket[beg + i + 1];
        float2 a = *(const float2*)&f[(size_t)r0 * DDIM + t * 2];
        float2 b = *(const float2*)&f[(size_t)r1 * DDIM + t * 2];
        acc.x += a.x + b.x;
        acc.y += a.y + b.y;
    }
    if (i < c) {
        int r0 = bucket[beg + i];
        float2 a = *(const float2*)&f[(size_t)r0 * DDIM + t * 2];
        acc.x += a.x;
        acc.y += a.y;
    }
    *(float2*)&dw[(size_t)j * DDIM + t * 2] = acc;
}

// ---------------------------------------------------------------------------
// Kernel 4: new_ecs = 0.99*ecs + 0.01*cnt; n = sum(new_ecs)
// ---------------------------------------------------------------------------
__global__ __launch_bounds__(256) void ecs_kernel(
    const float* __restrict__ ecs_in, const int* __restrict__ cnt,
    float* __restrict__ out_ecs, float* __restrict__ n_sum) {
    int i = blockIdx.x * 256 + threadIdx.x;
    float v = ecs_in[i] * EMA_DECAY_ + (1.0f - EMA_DECAY_) * (float)cnt[i];
    out_ecs[i] = v;
    float s = v;
#pragma unroll
    for (int off = 1; off < 64; off <<= 1) s += __shfl_xor(s, off, 64);
    if ((threadIdx.x & 63) == 0) atomicAdd(n_sum, s);
}

// ---------------------------------------------------------------------------
// Kernel 5: new_ema_w = 0.99*ema_w + 0.01*dw; new_K = new_ema_w / smoothed
// ---------------------------------------------------------------------------
__global__ __launch_bounds__(256) void final_kernel(
    const float* __restrict__ ema_w, const float* __restrict__ dw,
    const float* __restrict__ out_ecs, const float* __restrict__ n_sum,
    const float* __restrict__ loss_sum,
    float* __restrict__ out_K, float* __restrict__ out_emaw,
    float* __restrict__ out_loss) {
    int idx4 = blockIdx.x * 256 + threadIdx.x;   // 0..524287 (float4 granules)
    int row  = idx4 >> 7;                        // 128 float4 per row
    float n  = *n_sum;
    float smoothed = (out_ecs[row] + EPS_) / (n + KSZ_ * EPS_) * n;
    float inv = 1.0f / smoothed;
    size_t e = (size_t)idx4 * 4;
    float4 wv = *(const float4*)&ema_w[e];
    float4 dv = *(const float4*)&dw[e];
    float w0 = EMA_DECAY_ * wv.x + (1.0f - EMA_DECAY_) * dv.x;
    float w1 = EMA_DECAY_ * wv.y + (1.0f - EMA_DECAY_) * dv.y;
    float w2 = EMA_DECAY_ * wv.z + (1.0f - EMA_DECAY_) * dv.z;
    float w3 = EMA_DECAY_ * wv.w + (1.0f - EMA_DECAY_) * dv.w;
    out_emaw[e + 0] = w0; out_emaw[e + 1] = w1;
    out_emaw[e + 2] = w2; out_emaw[e + 3] = w3;
    out_K[e + 0] = w0 * inv; out_K[e + 1] = w1 * inv;
    out_K[e + 2] = w2 * inv; out_K[e + 3] = w3 * inv;
    if (idx4 == 0) *out_loss = *loss_sum * (1.0f / 16777216.0f);
}

// ---------------------------------------------------------------------------
// Workspace layout (float offsets):
//   0         Kt2       [4096]
//   4096      bestd     [32768*8]
//   266240    bestidx   [32768*8] (int)
//   528384    dw        [4096*512]      (fully written by dw_kernel)
//   2625536   loss_sum  [1]   <- zeroed
//   2625537   n_sum     [1]   <- zeroed
//   2625538   cnt       [4096] (int)    <- zeroed
//   2629634   cursor    [4096] (int)    <- zeroed
//   2633730   offs      [4096] (int)
//   2637826   k1        [32768] (int)
//   2670594   bucket    [32768] (int)
//   2703364   fh_swz    [8388608 floats worth of bf16]
//   11091972  fl_swz    [8388608]
//   19480580  kh_swz    [1048576]
//   20529156  kl_swz    [1048576]
// total 21577732 floats (~86.3 MB)
// ---------------------------------------------------------------------------
extern "C" void kernel_launch(void* const* d_in, const int* in_sizes, int n_in,
                              void* d_out, int out_size, void* d_ws, size_t ws_size,
                              hipStream_t stream) {
    const float* f     = (const float*)d_in[0];
    const float* K     = (const float*)d_in[1];
    const float* ecs   = (const float*)d_in[2];
    const float* ema_w = (const float*)d_in[3];

    float* ws       = (float*)d_ws;
    float* Kt2      = ws;
    float* bestd    = ws + 4096;
    int*   bestidx  = (int*)(ws + 266240);
    float* dw       = ws + 528384;
    float* loss_sum = ws + 2625536;
    float* n_sum    = ws + 2625537;
    int*   cnt      = (int*)(ws + 2625538);
    int*   cursor   = (int*)(ws + 2629634);
    int*   offs     = (int*)(ws + 2633730);
    int*   k1       = (int*)(ws + 2637826);
    int*   bucket   = (int*)(ws + 2670594);
    __bf16* fh      = (__bf16*)(ws + 2703364);
    __bf16* fl      = (__bf16*)(ws + 11091972);
    __bf16* kh      = (__bf16*)(ws + 19480580);
    __bf16* kl      = (__bf16*)(ws + 20529156);

    float* out      = (float*)d_out;
    float* out_fipm = out;                    // 16777216
    float* out_loss = out + 16777216;         // 1
    float* out_K    = out + 16777217;         // 2097152
    float* out_ecs  = out + 18874369;         // 4096
    float* out_emaw = out + 18878465;         // 2097152

    // zero accumulators: loss_sum + n_sum + cnt + cursor (contiguous, 32KB)
    hipMemsetAsync(loss_sum, 0, (size_t)(2 + 4096 + 4096) * sizeof(float), stream);

    // pre-convert f and K to swizzled bf16 hi/lo tiles
    convert_kernel<<<NROWS * DDIM / 8 / 256, 256, 0, stream>>>(f, fh, fl);
    convert_kernel<<<KSZ_ * DDIM / 8 / 256, 256, 0, stream>>>(K, kh, kl);

    kt2_kernel<<<KSZ_ * 64 / 256, 256, 0, stream>>>(K, Kt2);

    dim3 grid(NROWS / BM, CSPLIT);
    argmin_kernel<<<grid, 256, 0, stream>>>(fh, fl, kh, kl, Kt2, bestd, bestidx);

    reduce_kernel<<<NROWS / 256, 256, 0, stream>>>(bestd, bestidx, k1, cnt);
    scan_kernel<<<1, 256, 0, stream>>>(cnt, offs);
    scatter_kernel<<<NROWS / 256, 256, 0, stream>>>(k1, offs, cursor, bucket);

    gather_kernel<<<NROWS / 8 / 4, 256, 0, stream>>>(f, K, k1, out_fipm, loss_sum);

    dw_kernel<<<KSZ_, 256, 0, stream>>>(f, offs, cnt, bucket, dw);

    ecs_kernel<<<KSZ_ / 256, 256, 0, stream>>>(ecs, cnt, out_ecs, n_sum);

    final_kernel<<<(KSZ_ * DDIM / 4) / 256, 256, 0, stream>>>(
        ema_w, dw, out_ecs, n_sum, loss_sum, out_K, out_emaw, out_loss);
}